// Round 5
// baseline (146.790 us; speedup 1.0000x reference)
//
#include <hip/hip_runtime.h>
#include <math.h>

// Block-local Kalman filter, v5: single-barrier pipelined step.
//   Every block (256, one per CU via LDS pad): 9 waves.
//   Wave 0: serial Riccati via register GJ on [S | HP | I] (64 lanes:
//     16 S-cols, 32 HP-cols, 16 I-cols -> S^{-1}). Epilogue (lane-parallel):
//       isK lanes: K_t -> KT[t&1], HP_{t+1} = R G + HQ -> HPs
//       isI lanes (R diagonal): S_{t+1} = diag(R)(I - S^{-1}diag(R)) + S0 -> Sg
//     => wave 0 touches only its own LDS; no separate S phase, ONE
//     __syncthreads per step (KT handoff with consumers).
//   Waves 1-8: one batch each, consume K_{t-1} from KT[(t-1)&1].
//   Convergence (|dK|<=1e-5): all break; consumers run constant-K register
//   tail. F != I: sequential fallback. R non-diagonal: two-phase fallback.
// No workspace, no atomics, no inter-block communication.

#define S_DIM 32
#define O_DIM 16
#define HS 36          // padded fp32 stride for H-shaped tiles (144B rows)
#define CW 8           // consumer batches (= waves 1..8) per block
#define NTHR 576       // 9 waves

__device__ __forceinline__ float rdlanef(float v, int srcLane) {
    return __uint_as_float(
        (unsigned int)__builtin_amdgcn_readlane((int)__float_as_uint(v), srcLane));
}

__global__ __launch_bounds__(NTHR) void kf_fused(
    const float* __restrict__ state0,  // (B,32)
    const float* __restrict__ cov0,    // (B,32,32) -> batch 0
    const float* __restrict__ meas,    // (B,T,16)
    const float* __restrict__ Fm,      // (32,32)
    const float* __restrict__ Hm,      // (16,32)
    const float* __restrict__ Qm,      // (32,32)
    const float* __restrict__ Rm,      // (16,16)
    float* __restrict__ out,           // (B,T,32)
    int T, int B)
{
    const int tid = threadIdx.x;

    __shared__ float P  [S_DIM*33];
    __shared__ float Fs [S_DIM*33];
    __shared__ float Qs [S_DIM*33];
    __shared__ float Tp [S_DIM*33];
    __shared__ float Hs [O_DIM*HS];
    __shared__ float HQ [O_DIM*HS];
    __shared__ float HPs[O_DIM*HS];
    __shared__ float KT [2][O_DIM*33];   // K^T double buffer: KT[b][o*33+j]=K[j][o]
    __shared__ float Sg [O_DIM*17];
    __shared__ float Rs [O_DIM*17];
    __shared__ float S0g[O_DIM*17];      // S0 = HQ H^T + R (constant)
    __shared__ float xs [CW][32];
    __shared__ float iv [CW][16];
    __shared__ int notId, notDiag, convFlag, convT;
    // CU-isolation pad: static group segment > 80 KiB -> exactly 1 block/CU.
    __shared__ float cupad[13000];

    if (tid == 0) {
        ((volatile float*)cupad)[0] = 0.f;   // keep pad alive
        notId = 0; notDiag = 0; convFlag = 0; convT = 0;
    }

    // ---- stage shared parameters ----
    for (int i = tid; i < S_DIM*S_DIM; i += NTHR) {
        int r = i >> 5, c = i & 31;
        P [r*33+c] = cov0[i];
        Fs[r*33+c] = Fm[i];
        Qs[r*33+c] = Qm[i];
    }
    for (int i = tid; i < O_DIM*S_DIM; i += NTHR) {
        int r = i >> 5, c = i & 31;
        Hs[r*HS+c] = Hm[i];
    }
    for (int i = tid; i < O_DIM*O_DIM; i += NTHR) {
        int r = i >> 4, c = i & 15;
        Rs[r*17+c] = Rm[i];
    }
    __syncthreads();

    {   // F == I and R-diagonal detection (block-uniform, deterministic)
        bool badI = false, badD = false;
        for (int i = tid; i < S_DIM*S_DIM; i += NTHR) {
            int r = i >> 5, c = i & 31;
            if (Fs[r*33+c] != ((r == c) ? 1.0f : 0.0f)) badI = true;
        }
        for (int i = tid; i < O_DIM*O_DIM; i += NTHR) {
            int r = i >> 4, c = i & 15;
            if (r != c && Rs[r*17+c] != 0.0f) badD = true;
        }
        if (badI) notId = 1;
        if (badD) notDiag = 1;
    }
    __syncthreads();
    const bool fId   = (notId == 0);
    const bool rDiag = (notDiag == 0);

    // ---- consumer identities (waves 1..8) ----
    const int wv = tid >> 6;
    const int l  = tid & 63;
    const int s  = l & 31;
    const int h  = l >> 5;
    const int o  = l & 15;
    const int q  = l >> 4;
    const int wi = (wv >= 1) ? (wv - 1) : 0;
    const bool isCons = (wv >= 1);
    long bb = (long)blockIdx.x * CW + wi;
    const long b = (bb < B) ? bb : (B - 1);   // clamp: duplicate writes identical

    float4 h0v, h1v;
    {
        const float4* Hv = (const float4*)(Hm + o*S_DIM + q*8);
        h0v = Hv[0]; h1v = Hv[1];
    }

    float x = 0.f;
    if (isCons) {
        x = state0[b*S_DIM + s];
        if (h == 0) xs[wi][s] = x;
    }
    __syncthreads();

    // consumer step: x' = x + K_t (z_t - H x); K from KT[bufc] (K^T layout)
    auto cons_step = [&](int tstep, int bufc) {
        float za = meas[(b*T + tstep)*O_DIM + o];
        const float4* xq = (const float4*)(&xs[wi][q*8]);
        float4 xa = xq[0], xb = xq[1];
        float p = h0v.x*xa.x + h0v.y*xa.y + h0v.z*xa.z + h0v.w*xa.w
                + h1v.x*xb.x + h1v.y*xb.y + h1v.z*xb.z + h1v.w*xb.w;
        float p2 = p + __shfl_xor(p, 16, 64);
        float y  = p2 + __shfl_xor(p2, 32, 64);
        float innov = za - y;
        __builtin_amdgcn_wave_barrier();
        if (l < 16) iv[wi][o] = innov;
        __builtin_amdgcn_wave_barrier();
        const float* ivp = &iv[wi][h*8];
        const float* ktp = &KT[bufc][(h*8)*33 + s];
        float acc = 0.f;
        #pragma unroll
        for (int m = 0; m < 8; ++m) acc = fmaf(ktp[m*33], ivp[m], acc);
        float xnew = x + (acc + __shfl_xor(acc, 32, 64));
        if (h == 0) out[(b*T + tstep)*S_DIM + s] = xnew;
        __builtin_amdgcn_wave_barrier();
        if (h == 0) xs[wi][s] = xnew;
        __builtin_amdgcn_wave_barrier();
        x = xnew;
    };

    if (fId) {
        // ================= fast path: F == I, pipelined =================
        for (int i = tid; i < S_DIM*S_DIM; i += NTHR) {
            int r = i >> 5, c = i & 31;
            P[r*33+c] += Qs[r*33+c];           // P_pred_0 = P0 + Q
        }
        __syncthreads();
        if (tid < 512) {                        // HP_0 = H P_pred_0; HQ = H Q
            int r = tid >> 5, c = tid & 31;
            float a0 = 0.f, q0 = 0.f;
            for (int k = 0; k < S_DIM; ++k) {
                a0 += Hs[r*HS+k]*P [k*33+c];
                q0 += Hs[r*HS+k]*Qs[k*33+c];
            }
            HPs[r*HS+c] = a0;
            HQ [r*HS+c] = q0;
        }
        __syncthreads();
        if (tid < 256) {                        // S_0 = HP_0 H^T + R
            int r = tid >> 4, c = tid & 15;
            float a = Rs[r*17+c];
            const float4* hp = (const float4*)&HPs[r*HS];
            const float4* hh = (const float4*)&Hs [c*HS];
            #pragma unroll
            for (int k = 0; k < 8; ++k) {
                float4 u = hp[k], v = hh[k];
                a += u.x*v.x + u.y*v.y + u.z*v.z + u.w*v.w;
            }
            Sg[r*17+c] = a;
        } else if (tid < 512) {                 // S0 = HQ H^T + R (constant)
            int i = tid - 256;
            int r = i >> 4, c = i & 15;
            float a = Rs[r*17+c];
            const float4* hq = (const float4*)&HQ[r*HS];
            const float4* hh = (const float4*)&Hs[c*HS];
            #pragma unroll
            for (int k = 0; k < 8; ++k) {
                float4 u = hq[k], v = hh[k];
                a += u.x*v.x + u.y*v.y + u.z*v.z + u.w*v.w;
            }
            S0g[r*17+c] = a;
        }
        __syncthreads();

        // wave-0 register preload: R diagonal + S0 column (isI lanes)
        float Rd[16], s0c[16];
        if (tid < 64) {
            __builtin_amdgcn_s_setprio(1);
            #pragma unroll
            for (int r = 0; r < O_DIM; ++r) Rd[r] = Rs[r*17+r];
            if (tid >= 48) {
                const int lc = tid - 48;
                #pragma unroll
                for (int r = 0; r < O_DIM; ++r) s0c[r] = S0g[r*17+lc];
            }
        }

        float prevK[16];
        int t = 0;
        for (; t < T; ++t) {
            const int buf = t & 1;
            // ---- wave 0: GJ(t) on [S|HP|I]  ||  waves 1-8: cons(t-1) ----
            if (tid < 64) {
                const int myc = tid;
                const bool isS = (myc < O_DIM);
                const bool isK = (myc >= O_DIM && myc < 48);
                const bool isI = (myc >= 48);
                const int hc = (myc - O_DIM) & 31;
                const int lc = myc & 15;
                float a[16];
                #pragma unroll
                for (int r = 0; r < O_DIM; ++r) {
                    float v;
                    if (isS)      v = Sg[r*17+myc];
                    else if (isK) v = HPs[r*HS+hc];
                    else          v = (r == lc) ? 1.0f : 0.0f;
                    a[r] = v;
                }

                #pragma unroll
                for (int p = 0; p < O_DIM; ++p) {
                    float sp[16];
                    #pragma unroll
                    for (int r = 0; r < O_DIM; ++r) sp[r] = rdlanef(a[r], p);
                    float pinv = __builtin_amdgcn_rcpf(sp[p]);
                    float sc = a[p] * pinv;
                    #pragma unroll
                    for (int r = 0; r < O_DIM; ++r)
                        a[r] = (r == p) ? sc : fmaf(-sp[r], sc, a[r]);
                }

                float d = 0.f;
                if (isK) {
                    #pragma unroll
                    for (int r = 0; r < O_DIM; ++r) {
                        float dd = fabsf(a[r] - prevK[r]);
                        d = fmaxf(d, dd);
                        prevK[r] = a[r];
                    }
                }
                unsigned long long anyBig = __ballot(isK && (d > 1e-5f));
                if (myc == 0 && anyBig == 0ull && t >= 1) {
                    convFlag = 1; convT = t;
                }

                if (isK) {
                    const int j = myc - O_DIM;
                    #pragma unroll
                    for (int oo = 0; oo < O_DIM; ++oo) KT[buf][oo*33+j] = a[oo];
                    // HP_next = R G + HQ
                    if (rDiag) {
                        #pragma unroll
                        for (int r = 0; r < O_DIM; ++r)
                            HPs[r*HS+j] = fmaf(Rd[r], a[r], HQ[r*HS+j]);
                    } else {
                        #pragma unroll
                        for (int r = 0; r < O_DIM; ++r) {
                            float rg = 0.f;
                            for (int k = 0; k < O_DIM; ++k) rg += Rs[r*17+k]*a[k];
                            HPs[r*HS+j] = rg + HQ[r*HS+j];
                        }
                    }
                }
                if (isI && rDiag) {
                    // S_{t+1}[r][lc] = Rd[r]*d_rlc - Rd[r]*Rd[lc]*Sinv[r][lc] + S0
                    float rc = Rd[lc];
                    #pragma unroll
                    for (int r = 0; r < O_DIM; ++r) {
                        float v = fmaf(-(Rd[r]*rc), a[r], s0c[r]);
                        if (r == lc) v += Rd[r];
                        Sg[r*17+lc] = v;
                    }
                }
            } else if (isCons && t > 0) {
                cons_step(t - 1, buf ^ 1);
            }
            __syncthreads();   // KT handoff (the ONLY per-step barrier, rDiag)

            if (convFlag) break;   // block-uniform

            if (!rDiag && t + 1 < T) {   // fallback: S(t+1) with 256 threads
                if (tid < 256) {
                    int r = tid >> 4, c = tid & 15;
                    float a = Rs[r*17+c];
                    const float4* hp = (const float4*)&HPs[r*HS];
                    const float4* hh = (const float4*)&Hs [c*HS];
                    #pragma unroll
                    for (int k = 0; k < 8; ++k) {
                        float4 u = hp[k], v = hh[k];
                        a += u.x*v.x + u.y*v.y + u.z*v.z + u.w*v.w;
                    }
                    Sg[r*17+c] = a;
                }
                __syncthreads();
            }
        }
        if (tid < 64) __builtin_amdgcn_s_setprio(0);

        if (!isCons) return;

        if (!convFlag) {
            // no early convergence: finish the last step and exit
            cons_step(T - 1, (T - 1) & 1);
            return;
        }

        // ============== constant-K tail: steps convT..T-1 ==============
        const int tc  = convT;
        const int bufc = tc & 1;
        float ka[16];
        #pragma unroll
        for (int j = 0; j < 16; ++j) ka[j] = KT[bufc][j*33 + s];

        float4 kc0, kc1;
        kc0.x = h ? ka[8]  : ka[0];  kc0.y = h ? ka[9]  : ka[1];
        kc0.z = h ? ka[10] : ka[2];  kc0.w = h ? ka[11] : ka[3];
        kc1.x = h ? ka[12] : ka[4];  kc1.y = h ? ka[13] : ka[5];
        kc1.z = h ? ka[14] : ka[6];  kc1.w = h ? ka[15] : ka[7];

        float mreg[16];
        #pragma unroll
        for (int j = 0; j < 16; ++j)
            mreg[j] = (s == h*16 + j) ? 1.0f : 0.0f;
        for (int oo = 0; oo < O_DIM; ++oo) {
            const float4* Hr = (const float4*)&Hs[oo*HS + h*16];
            float4 a0 = Hr[0], a1 = Hr[1], a2 = Hr[2], a3 = Hr[3];
            float k = ka[oo];
            mreg[0]  = fmaf(-k, a0.x, mreg[0]);
            mreg[1]  = fmaf(-k, a0.y, mreg[1]);
            mreg[2]  = fmaf(-k, a0.z, mreg[2]);
            mreg[3]  = fmaf(-k, a0.w, mreg[3]);
            mreg[4]  = fmaf(-k, a1.x, mreg[4]);
            mreg[5]  = fmaf(-k, a1.y, mreg[5]);
            mreg[6]  = fmaf(-k, a1.z, mreg[6]);
            mreg[7]  = fmaf(-k, a1.w, mreg[7]);
            mreg[8]  = fmaf(-k, a2.x, mreg[8]);
            mreg[9]  = fmaf(-k, a2.y, mreg[9]);
            mreg[10] = fmaf(-k, a2.z, mreg[10]);
            mreg[11] = fmaf(-k, a2.w, mreg[11]);
            mreg[12] = fmaf(-k, a3.x, mreg[12]);
            mreg[13] = fmaf(-k, a3.y, mreg[13]);
            mreg[14] = fmaf(-k, a3.z, mreg[14]);
            mreg[15] = fmaf(-k, a3.w, mreg[15]);
        }

        int t2 = tc;
        // z prefetch (depth-2), half rows: z[8h .. 8h+8)
        float4 zva0, zva1, zvb0, zvb1;
        {
            const float4* Zv = (const float4*)(meas + (b*T + t2)*O_DIM + h*8);
            zva0 = Zv[0]; zva1 = Zv[1];
            const int t1 = (t2 + 1 < T) ? (t2 + 1) : t2;
            const float4* Zv1 = (const float4*)(meas + (b*T + t1)*O_DIM + h*8);
            zvb0 = Zv1[0]; zvb1 = Zv1[1];
        }

        for (; t2 < T; ++t2) {
            float4 zvc0, zvc1;
            {
                const int tn = (t2 + 2 < T) ? (t2 + 2) : (T - 1);
                const float4* Zv = (const float4*)(meas + (b*T + tn)*O_DIM + h*8);
                zvc0 = Zv[0]; zvc1 = Zv[1];
            }

            const float4* xv = (const float4*)(&xs[wi][h*16]);
            float4 xa = xv[0], xb = xv[1], xc = xv[2], xd = xv[3];
            float p = mreg[0] *xa.x + mreg[1] *xa.y + mreg[2] *xa.z + mreg[3] *xa.w
                    + mreg[4] *xb.x + mreg[5] *xb.y + mreg[6] *xb.z + mreg[7] *xb.w
                    + mreg[8] *xc.x + mreg[9] *xc.y + mreg[10]*xc.z + mreg[11]*xc.w
                    + mreg[12]*xd.x + mreg[13]*xd.y + mreg[14]*xd.z + mreg[15]*xd.w;
            p += kc0.x*zva0.x + kc0.y*zva0.y + kc0.z*zva0.z + kc0.w*zva0.w
               + kc1.x*zva1.x + kc1.y*zva1.y + kc1.z*zva1.z + kc1.w*zva1.w;
            float xnew = p + __shfl_xor(p, 32, 64);

            if (h == 0) out[(b*T + t2)*S_DIM + s] = xnew;

            __builtin_amdgcn_wave_barrier();
            if (h == 0) xs[wi][s] = xnew;
            __builtin_amdgcn_wave_barrier();

            zva0 = zvb0; zva1 = zvb1;
            zvb0 = zvc0; zvb1 = zvc1;
        }
        return;
    }

    // ================= general path: F != I, sequential =================
    float4 f0, f1, f2, f3;
    if (isCons) {
        const float4* Fv = (const float4*)(Fm + s*S_DIM + h*16);
        f0 = Fv[0]; f1 = Fv[1]; f2 = Fv[2]; f3 = Fv[3];
    }

    for (int t = 0; t < T; ++t) {
        // predict: P = F P F^T + Q; HP = H P
        for (int i = tid; i < S_DIM*S_DIM; i += NTHR) {
            int r = i >> 5, c = i & 31;
            float a = 0.f;
            for (int k = 0; k < S_DIM; ++k) a += Fs[r*33+k]*P[k*33+c];
            Tp[r*33+c] = a;
        }
        __syncthreads();
        for (int i = tid; i < S_DIM*S_DIM; i += NTHR) {
            int r = i >> 5, c = i & 31;
            float a = Qs[r*33+c];
            for (int k = 0; k < S_DIM; ++k) a += Tp[r*33+k]*Fs[c*33+k];
            P[r*33+c] = a;
        }
        __syncthreads();
        if (tid < 512) {
            int r = tid >> 5, c = tid & 31;
            float a = 0.f;
            for (int k = 0; k < S_DIM; ++k) a += Hs[r*HS+k]*P[k*33+c];
            HPs[r*HS+c] = a;
        }
        __syncthreads();
        if (tid < 256) {   // S = HP H^T + R
            int r = tid >> 4, c = tid & 15;
            float a = Rs[r*17+c];
            const float4* hp = (const float4*)&HPs[r*HS];
            const float4* hh = (const float4*)&Hs [c*HS];
            #pragma unroll
            for (int k = 0; k < 8; ++k) {
                float4 u = hp[k], v = hh[k];
                a += u.x*v.x + u.y*v.y + u.z*v.z + u.w*v.w;
            }
            Sg[r*17+c] = a;
        }
        __syncthreads();
        if (tid < 64) {    // GJ -> KT[0]
            const int myc = tid;
            const bool isS = (myc < O_DIM);
            const bool isK = (!isS && myc < 48);
            const int hc = (myc - O_DIM) & 31;
            float a[16];
            #pragma unroll
            for (int r = 0; r < O_DIM; ++r)
                a[r] = isS ? Sg[r*17+myc] : HPs[r*HS+hc];
            #pragma unroll
            for (int p = 0; p < O_DIM; ++p) {
                float sp[16];
                #pragma unroll
                for (int r = 0; r < O_DIM; ++r) sp[r] = rdlanef(a[r], p);
                float pinv = __builtin_amdgcn_rcpf(sp[p]);
                float sc = a[p] * pinv;
                #pragma unroll
                for (int r = 0; r < O_DIM; ++r)
                    a[r] = (r == p) ? sc : fmaf(-sp[r], sc, a[r]);
            }
            if (isK) {
                const int j = myc - O_DIM;
                #pragma unroll
                for (int oo = 0; oo < O_DIM; ++oo) KT[0][oo*33+j] = a[oo];
            }
        }
        __syncthreads();

        if (isCons) {
            // x_pred = F x
            const float4* xv = (const float4*)(&xs[wi][h*16]);
            float4 xa = xv[0], xb = xv[1], xc = xv[2], xd = xv[3];
            float pr = f0.x*xa.x + f0.y*xa.y + f0.z*xa.z + f0.w*xa.w
                     + f1.x*xb.x + f1.y*xb.y + f1.z*xb.z + f1.w*xb.w
                     + f2.x*xc.x + f2.y*xc.y + f2.z*xc.z + f2.w*xc.w
                     + f3.x*xd.x + f3.y*xd.y + f3.z*xd.z + f3.w*xd.w;
            x = pr + __shfl_xor(pr, 32, 64);
            __builtin_amdgcn_wave_barrier();
            if (h == 0) xs[wi][s] = x;
            __builtin_amdgcn_wave_barrier();
            cons_step(t, 0);
        }

        // P -= K^T (HP)  [update]
        for (int i = tid; i < S_DIM*S_DIM; i += NTHR) {
            int r = i >> 5, c = i & 31;
            float acc = 0.f;
            for (int oo = 0; oo < O_DIM; ++oo)
                acc += KT[0][oo*33+r]*HPs[oo*HS+c];
            P[r*33+c] -= acc;
        }
        __syncthreads();
    }
}

extern "C" void kernel_launch(void* const* d_in, const int* in_sizes, int n_in,
                              void* d_out, int out_size, void* d_ws, size_t ws_size,
                              hipStream_t stream) {
    const float* state0 = (const float*)d_in[0];
    const float* cov0   = (const float*)d_in[1];
    const float* meas   = (const float*)d_in[2];
    const float* Fm     = (const float*)d_in[3];
    const float* Hm     = (const float*)d_in[4];
    const float* Qm     = (const float*)d_in[5];
    const float* Rm     = (const float*)d_in[6];
    float* out = (float*)d_out;

    const int B = in_sizes[0] / S_DIM;               // 2048
    const int T = in_sizes[2] / (B * O_DIM);         // 64

    const int grid = (B + CW - 1) / CW;              // 256 blocks
    kf_fused<<<dim3(grid), dim3(NTHR), 0, stream>>>(
        state0, cov0, meas, Fm, Hm, Qm, Rm, out, T, B);
}

// Round 6
// 144.592 us; speedup vs baseline: 1.0152x; 1.0152x over previous
//
#include <hip/hip_runtime.h>
#include <math.h>

// Block-local Kalman filter, v6: register-resident Riccati, single barrier.
//   Every block (256, one per CU via LDS pad): 9 waves.
//   Wave 0: serial Riccati via register GJ on [S | HP | I] (64 lanes = cols).
//     Lane ownership persists across t:
//       isK lane j: epilogue HP_{t+1}[:,j] = r0*G[:,j] + HQ[:,j] stays IN a[]
//         (no HPs LDS traffic after prologue).
//       isI lane lc: epilogue S_{t+1}[:,lc] = S0 + r0*I - r0^2 * Sinv[:,lc]
//         stays in a[]; isS lanes fetch it next step via __shfl (no Sg LDS).
//     Only per-step LDS: KT[t&1] writes (consumer handoff). ONE barrier/step.
//     Register diet: aux1[16] = prevK (isK) | s0c (isI); scalar r0 (R = r0*I
//     detected; non-scalar diag falls back to LDS reads of Rs diagonal).
//   Waves 1-8: one batch each, consume K_{t-1} from KT[(t-1)&1].
//   Convergence (|dK|<=1e-5): all break; consumers run constant-K register
//   tail. F != I or R non-diagonal: sequential general fallback.
// No workspace, no atomics, no inter-block communication.

#define S_DIM 32
#define O_DIM 16
#define HS 36          // padded fp32 stride for H-shaped tiles (144B rows)
#define CW 8           // consumer batches (= waves 1..8) per block
#define NTHR 576       // 9 waves

__device__ __forceinline__ float rdlanef(float v, int srcLane) {
    return __uint_as_float(
        (unsigned int)__builtin_amdgcn_readlane((int)__float_as_uint(v), srcLane));
}

__global__ __launch_bounds__(NTHR) void kf_fused(
    const float* __restrict__ state0,  // (B,32)
    const float* __restrict__ cov0,    // (B,32,32) -> batch 0
    const float* __restrict__ meas,    // (B,T,16)
    const float* __restrict__ Fm,      // (32,32)
    const float* __restrict__ Hm,      // (16,32)
    const float* __restrict__ Qm,      // (32,32)
    const float* __restrict__ Rm,      // (16,16)
    float* __restrict__ out,           // (B,T,32)
    int T, int B)
{
    const int tid = threadIdx.x;

    __shared__ float P  [S_DIM*33];
    __shared__ float Fs [S_DIM*33];
    __shared__ float Qs [S_DIM*33];
    __shared__ float Tp [S_DIM*33];
    __shared__ float Hs [O_DIM*HS];
    __shared__ float HQ [O_DIM*HS];
    __shared__ float HPs[O_DIM*HS];
    __shared__ float KT [2][O_DIM*33];   // K^T double buffer: KT[b][o*33+j]=K[j][o]
    __shared__ float Sg [O_DIM*17];
    __shared__ float Rs [O_DIM*17];
    __shared__ float S0g[O_DIM*17];      // S0 = HQ H^T + R (constant)
    __shared__ float xs [CW][32];
    __shared__ float iv [CW][16];
    __shared__ int notId, notDiag, notScal, convFlag, convT;
    // CU-isolation pad: static group segment > 80 KiB -> exactly 1 block/CU.
    __shared__ float cupad[13000];

    if (tid == 0) {
        ((volatile float*)cupad)[0] = 0.f;   // keep pad alive
        notId = 0; notDiag = 0; notScal = 0; convFlag = 0; convT = 0;
    }

    // ---- stage shared parameters ----
    for (int i = tid; i < S_DIM*S_DIM; i += NTHR) {
        int r = i >> 5, c = i & 31;
        P [r*33+c] = cov0[i];
        Fs[r*33+c] = Fm[i];
        Qs[r*33+c] = Qm[i];
    }
    for (int i = tid; i < O_DIM*S_DIM; i += NTHR) {
        int r = i >> 5, c = i & 31;
        Hs[r*HS+c] = Hm[i];
    }
    for (int i = tid; i < O_DIM*O_DIM; i += NTHR) {
        int r = i >> 4, c = i & 15;
        Rs[r*17+c] = Rm[i];
    }
    __syncthreads();

    {   // F == I, R-diagonal, R-scalar detection (block-uniform)
        bool badI = false, badD = false, badS = false;
        float r00 = Rs[0];
        for (int i = tid; i < S_DIM*S_DIM; i += NTHR) {
            int r = i >> 5, c = i & 31;
            if (Fs[r*33+c] != ((r == c) ? 1.0f : 0.0f)) badI = true;
        }
        for (int i = tid; i < O_DIM*O_DIM; i += NTHR) {
            int r = i >> 4, c = i & 15;
            if (r != c && Rs[r*17+c] != 0.0f) badD = true;
            if (r == c && Rs[r*17+c] != r00)  badS = true;
        }
        if (badI) notId = 1;
        if (badD) notDiag = 1;
        if (badS) notScal = 1;
    }
    __syncthreads();
    const bool fId   = (notId == 0);
    const bool rDiag = (notDiag == 0);
    const bool rScal = rDiag && (notScal == 0);

    // ---- consumer identities (waves 1..8) ----
    const int wv = tid >> 6;
    const int l  = tid & 63;
    const int s  = l & 31;
    const int h  = l >> 5;
    const int o  = l & 15;
    const int q  = l >> 4;
    const int wi = (wv >= 1) ? (wv - 1) : 0;
    const bool isCons = (wv >= 1);
    long bb = (long)blockIdx.x * CW + wi;
    const long b = (bb < B) ? bb : (B - 1);   // clamp: duplicate writes identical

    float4 h0v, h1v;
    {
        const float4* Hv = (const float4*)(Hm + o*S_DIM + q*8);
        h0v = Hv[0]; h1v = Hv[1];
    }

    float x = 0.f;
    if (isCons) {
        x = state0[b*S_DIM + s];
        if (h == 0) xs[wi][s] = x;
    }
    __syncthreads();

    // consumer step: x' = x + K_t (z_t - H x); K from KT[bufc] (K^T layout)
    auto cons_step = [&](int tstep, int bufc) {
        float za = meas[(b*T + tstep)*O_DIM + o];
        const float4* xq = (const float4*)(&xs[wi][q*8]);
        float4 xa = xq[0], xb = xq[1];
        float p = h0v.x*xa.x + h0v.y*xa.y + h0v.z*xa.z + h0v.w*xa.w
                + h1v.x*xb.x + h1v.y*xb.y + h1v.z*xb.z + h1v.w*xb.w;
        float p2 = p + __shfl_xor(p, 16, 64);
        float y  = p2 + __shfl_xor(p2, 32, 64);
        float innov = za - y;
        __builtin_amdgcn_wave_barrier();
        if (l < 16) iv[wi][o] = innov;
        __builtin_amdgcn_wave_barrier();
        const float* ivp = &iv[wi][h*8];
        const float* ktp = &KT[bufc][(h*8)*33 + s];
        float acc = 0.f;
        #pragma unroll
        for (int m = 0; m < 8; ++m) acc = fmaf(ktp[m*33], ivp[m], acc);
        float xnew = x + (acc + __shfl_xor(acc, 32, 64));
        if (h == 0) out[(b*T + tstep)*S_DIM + s] = xnew;
        __builtin_amdgcn_wave_barrier();
        if (h == 0) xs[wi][s] = xnew;
        __builtin_amdgcn_wave_barrier();
        x = xnew;
    };

    if (fId && rDiag) {
        // ========== fast path: F == I, R diagonal, register-resident ==========
        for (int i = tid; i < S_DIM*S_DIM; i += NTHR) {
            int r = i >> 5, c = i & 31;
            P[r*33+c] += Qs[r*33+c];           // P_pred_0 = P0 + Q
        }
        __syncthreads();
        if (tid < 512) {                        // HP_0 = H P_pred_0; HQ = H Q
            int r = tid >> 5, c = tid & 31;
            float a0 = 0.f, q0 = 0.f;
            for (int k = 0; k < S_DIM; ++k) {
                a0 += Hs[r*HS+k]*P [k*33+c];
                q0 += Hs[r*HS+k]*Qs[k*33+c];
            }
            HPs[r*HS+c] = a0;
            HQ [r*HS+c] = q0;
        }
        __syncthreads();
        if (tid < 256) {                        // S_0 = HP_0 H^T + R
            int r = tid >> 4, c = tid & 15;
            float a = Rs[r*17+c];
            const float4* hp = (const float4*)&HPs[r*HS];
            const float4* hh = (const float4*)&Hs [c*HS];
            #pragma unroll
            for (int k = 0; k < 8; ++k) {
                float4 u = hp[k], v = hh[k];
                a += u.x*v.x + u.y*v.y + u.z*v.z + u.w*v.w;
            }
            Sg[r*17+c] = a;
        } else if (tid < 512) {                 // S0 = HQ H^T + R (constant)
            int i = tid - 256;
            int r = i >> 4, c = i & 15;
            float a = Rs[r*17+c];
            const float4* hq = (const float4*)&HQ[r*HS];
            const float4* hh = (const float4*)&Hs[c*HS];
            #pragma unroll
            for (int k = 0; k < 8; ++k) {
                float4 u = hq[k], v = hh[k];
                a += u.x*v.x + u.y*v.y + u.z*v.z + u.w*v.w;
            }
            S0g[r*17+c] = a;
        }
        __syncthreads();

        // ---- wave-0 register state ----
        // a[16]   : my matrix column (persistent across t)
        // aux1[16]: prevK (isK) | s0 column (isI)  -- overlaid, never cross-used
        // hqc[16] : HQ column (isK only)
        float a[16], aux1[16], hqc[16];
        float r0 = 0.f, rcL = 0.f;
        const int myc  = tid;          // valid for tid<64
        const int lc16 = myc & 15;
        const bool isS = (myc < O_DIM);
        const bool isK = (myc >= O_DIM && myc < 48);
        const bool isI = (myc >= 48);
        const int j = myc - O_DIM;     // isK column index 0..31
        if (tid < 64) {
            __builtin_amdgcn_s_setprio(1);
            r0  = Rs[0];
            rcL = rScal ? r0 : Rs[lc16*17+lc16];
            #pragma unroll
            for (int r = 0; r < O_DIM; ++r) {
                float v;
                if (isS)      v = Sg[r*17+myc];
                else if (isK) v = HPs[r*HS+j];
                else          v = (r == lc16) ? 1.0f : 0.0f;
                a[r] = v;
                float av;
                if (isI)      av = S0g[r*17+lc16];
                else          av = 0.f;          // prevK init (gated by t>=1)
                aux1[r] = av;
                hqc[r] = isK ? HQ[r*HS+j] : 0.f;
            }
        }

        int t = 0;
        for (; t < T; ++t) {
            const int buf = t & 1;
            if (tid < 64) {
                // ---- handoff: isS fetch S_t col from isI; isI reset to I ----
                if (t > 0) {
                    #pragma unroll
                    for (int r = 0; r < O_DIM; ++r) {
                        float sv = __shfl(a[r], 48 + lc16, 64);
                        if (isS) a[r] = sv;
                        else if (isI) a[r] = (r == lc16) ? 1.0f : 0.0f;
                    }
                }

                // ---- GJ on [S | HP | I] ----
                #pragma unroll
                for (int p = 0; p < O_DIM; ++p) {
                    float sp[16];
                    #pragma unroll
                    for (int r = 0; r < O_DIM; ++r) sp[r] = rdlanef(a[r], p);
                    float pinv = __builtin_amdgcn_rcpf(sp[p]);
                    float sc = a[p] * pinv;
                    #pragma unroll
                    for (int r = 0; r < O_DIM; ++r)
                        a[r] = (r == p) ? sc : fmaf(-sp[r], sc, a[r]);
                }

                // ---- convergence (isK: a[] is K column now) ----
                float d = 0.f;
                if (isK) {
                    #pragma unroll
                    for (int r = 0; r < O_DIM; ++r) {
                        float dd = fabsf(a[r] - aux1[r]);
                        d = fmaxf(d, dd);
                        aux1[r] = a[r];
                    }
                }
                unsigned long long anyBig = __ballot(isK && (d > 1e-5f));
                if (myc == 0 && anyBig == 0ull && t >= 1) {
                    convFlag = 1; convT = t;
                }

                // ---- epilogue: KT handoff + next-state in registers ----
                if (isK) {
                    #pragma unroll
                    for (int oo = 0; oo < O_DIM; ++oo) KT[buf][oo*33+j] = a[oo];
                    #pragma unroll
                    for (int r = 0; r < O_DIM; ++r) {
                        float rr = rScal ? r0 : Rs[r*17+r];
                        a[r] = fmaf(rr, a[r], hqc[r]);       // HP_{t+1} column
                    }
                }
                if (isI) {
                    #pragma unroll
                    for (int r = 0; r < O_DIM; ++r) {
                        float rr = rScal ? r0 : Rs[r*17+r];
                        float v = fmaf(-(rr*rcL), a[r], aux1[r]);
                        if (r == lc16) v += rr;
                        a[r] = v;                            // S_{t+1} column
                    }
                }
            } else if (isCons && t > 0) {
                cons_step(t - 1, buf ^ 1);
            }
            __syncthreads();   // KT handoff: the ONLY per-step barrier

            if (convFlag) break;   // block-uniform
        }
        if (tid < 64) __builtin_amdgcn_s_setprio(0);

        if (!isCons) return;

        if (!convFlag) {
            cons_step(T - 1, (T - 1) & 1);
            return;
        }

        // ============== constant-K tail: steps convT..T-1 ==============
        const int tc  = convT;
        const int bufc = tc & 1;
        float ka[16];
        #pragma unroll
        for (int jj = 0; jj < 16; ++jj) ka[jj] = KT[bufc][jj*33 + s];

        float4 kc0, kc1;
        kc0.x = h ? ka[8]  : ka[0];  kc0.y = h ? ka[9]  : ka[1];
        kc0.z = h ? ka[10] : ka[2];  kc0.w = h ? ka[11] : ka[3];
        kc1.x = h ? ka[12] : ka[4];  kc1.y = h ? ka[13] : ka[5];
        kc1.z = h ? ka[14] : ka[6];  kc1.w = h ? ka[15] : ka[7];

        float mreg[16];
        #pragma unroll
        for (int jj = 0; jj < 16; ++jj)
            mreg[jj] = (s == h*16 + jj) ? 1.0f : 0.0f;
        for (int oo = 0; oo < O_DIM; ++oo) {
            const float4* Hr = (const float4*)&Hs[oo*HS + h*16];
            float4 a0 = Hr[0], a1 = Hr[1], a2 = Hr[2], a3 = Hr[3];
            float k = ka[oo];
            mreg[0]  = fmaf(-k, a0.x, mreg[0]);
            mreg[1]  = fmaf(-k, a0.y, mreg[1]);
            mreg[2]  = fmaf(-k, a0.z, mreg[2]);
            mreg[3]  = fmaf(-k, a0.w, mreg[3]);
            mreg[4]  = fmaf(-k, a1.x, mreg[4]);
            mreg[5]  = fmaf(-k, a1.y, mreg[5]);
            mreg[6]  = fmaf(-k, a1.z, mreg[6]);
            mreg[7]  = fmaf(-k, a1.w, mreg[7]);
            mreg[8]  = fmaf(-k, a2.x, mreg[8]);
            mreg[9]  = fmaf(-k, a2.y, mreg[9]);
            mreg[10] = fmaf(-k, a2.z, mreg[10]);
            mreg[11] = fmaf(-k, a2.w, mreg[11]);
            mreg[12] = fmaf(-k, a3.x, mreg[12]);
            mreg[13] = fmaf(-k, a3.y, mreg[13]);
            mreg[14] = fmaf(-k, a3.z, mreg[14]);
            mreg[15] = fmaf(-k, a3.w, mreg[15]);
        }

        int t2 = tc;
        float4 zva0, zva1, zvb0, zvb1;
        {
            const float4* Zv = (const float4*)(meas + (b*T + t2)*O_DIM + h*8);
            zva0 = Zv[0]; zva1 = Zv[1];
            const int t1 = (t2 + 1 < T) ? (t2 + 1) : t2;
            const float4* Zv1 = (const float4*)(meas + (b*T + t1)*O_DIM + h*8);
            zvb0 = Zv1[0]; zvb1 = Zv1[1];
        }

        for (; t2 < T; ++t2) {
            float4 zvc0, zvc1;
            {
                const int tn = (t2 + 2 < T) ? (t2 + 2) : (T - 1);
                const float4* Zv = (const float4*)(meas + (b*T + tn)*O_DIM + h*8);
                zvc0 = Zv[0]; zvc1 = Zv[1];
            }

            const float4* xv = (const float4*)(&xs[wi][h*16]);
            float4 xa = xv[0], xb = xv[1], xc = xv[2], xd = xv[3];
            float p = mreg[0] *xa.x + mreg[1] *xa.y + mreg[2] *xa.z + mreg[3] *xa.w
                    + mreg[4] *xb.x + mreg[5] *xb.y + mreg[6] *xb.z + mreg[7] *xb.w
                    + mreg[8] *xc.x + mreg[9] *xc.y + mreg[10]*xc.z + mreg[11]*xc.w
                    + mreg[12]*xd.x + mreg[13]*xd.y + mreg[14]*xd.z + mreg[15]*xd.w;
            p += kc0.x*zva0.x + kc0.y*zva0.y + kc0.z*zva0.z + kc0.w*zva0.w
               + kc1.x*zva1.x + kc1.y*zva1.y + kc1.z*zva1.z + kc1.w*zva1.w;
            float xnew = p + __shfl_xor(p, 32, 64);

            if (h == 0) out[(b*T + t2)*S_DIM + s] = xnew;

            __builtin_amdgcn_wave_barrier();
            if (h == 0) xs[wi][s] = xnew;
            __builtin_amdgcn_wave_barrier();

            zva0 = zvb0; zva1 = zvb1;
            zvb0 = zvc0; zvb1 = zvc1;
        }
        return;
    }

    // ============ general path: F != I or R non-diagonal, sequential ============
    float4 f0, f1, f2, f3;
    if (isCons) {
        const float4* Fv = (const float4*)(Fm + s*S_DIM + h*16);
        f0 = Fv[0]; f1 = Fv[1]; f2 = Fv[2]; f3 = Fv[3];
    }

    for (int t = 0; t < T; ++t) {
        // predict: P = F P F^T + Q; HP = H P
        for (int i = tid; i < S_DIM*S_DIM; i += NTHR) {
            int r = i >> 5, c = i & 31;
            float a = 0.f;
            for (int k = 0; k < S_DIM; ++k) a += Fs[r*33+k]*P[k*33+c];
            Tp[r*33+c] = a;
        }
        __syncthreads();
        for (int i = tid; i < S_DIM*S_DIM; i += NTHR) {
            int r = i >> 5, c = i & 31;
            float a = Qs[r*33+c];
            for (int k = 0; k < S_DIM; ++k) a += Tp[r*33+k]*Fs[c*33+k];
            P[r*33+c] = a;
        }
        __syncthreads();
        if (tid < 512) {
            int r = tid >> 5, c = tid & 31;
            float a = 0.f;
            for (int k = 0; k < S_DIM; ++k) a += Hs[r*HS+k]*P[k*33+c];
            HPs[r*HS+c] = a;
        }
        __syncthreads();
        if (tid < 256) {   // S = HP H^T + R
            int r = tid >> 4, c = tid & 15;
            float a = Rs[r*17+c];
            const float4* hp = (const float4*)&HPs[r*HS];
            const float4* hh = (const float4*)&Hs [c*HS];
            #pragma unroll
            for (int k = 0; k < 8; ++k) {
                float4 u = hp[k], v = hh[k];
                a += u.x*v.x + u.y*v.y + u.z*v.z + u.w*v.w;
            }
            Sg[r*17+c] = a;
        }
        __syncthreads();
        if (tid < 64) {    // GJ -> KT[0]
            const int myc = tid;
            const bool isS = (myc < O_DIM);
            const bool isK = (!isS && myc < 48);
            const int hc = (myc - O_DIM) & 31;
            float a[16];
            #pragma unroll
            for (int r = 0; r < O_DIM; ++r)
                a[r] = isS ? Sg[r*17+myc] : HPs[r*HS+hc];
            #pragma unroll
            for (int p = 0; p < O_DIM; ++p) {
                float sp[16];
                #pragma unroll
                for (int r = 0; r < O_DIM; ++r) sp[r] = rdlanef(a[r], p);
                float pinv = __builtin_amdgcn_rcpf(sp[p]);
                float sc = a[p] * pinv;
                #pragma unroll
                for (int r = 0; r < O_DIM; ++r)
                    a[r] = (r == p) ? sc : fmaf(-sp[r], sc, a[r]);
            }
            if (isK) {
                const int jj = myc - O_DIM;
                #pragma unroll
                for (int oo = 0; oo < O_DIM; ++oo) KT[0][oo*33+jj] = a[oo];
            }
        }
        __syncthreads();

        if (isCons) {
            // x_pred = F x
            const float4* xv = (const float4*)(&xs[wi][h*16]);
            float4 xa = xv[0], xb = xv[1], xc = xv[2], xd = xv[3];
            float pr = f0.x*xa.x + f0.y*xa.y + f0.z*xa.z + f0.w*xa.w
                     + f1.x*xb.x + f1.y*xb.y + f1.z*xb.z + f1.w*xb.w
                     + f2.x*xc.x + f2.y*xc.y + f2.z*xc.z + f2.w*xc.w
                     + f3.x*xd.x + f3.y*xd.y + f3.z*xd.z + f3.w*xd.w;
            x = pr + __shfl_xor(pr, 32, 64);
            __builtin_amdgcn_wave_barrier();
            if (h == 0) xs[wi][s] = x;
            __builtin_amdgcn_wave_barrier();
            cons_step(t, 0);
        }

        // P -= K^T (HP)  [update]
        for (int i = tid; i < S_DIM*S_DIM; i += NTHR) {
            int r = i >> 5, c = i & 31;
            float acc = 0.f;
            for (int oo = 0; oo < O_DIM; ++oo)
                acc += KT[0][oo*33+r]*HPs[oo*HS+c];
            P[r*33+c] -= acc;
        }
        __syncthreads();
    }
}

extern "C" void kernel_launch(void* const* d_in, const int* in_sizes, int n_in,
                              void* d_out, int out_size, void* d_ws, size_t ws_size,
                              hipStream_t stream) {
    const float* state0 = (const float*)d_in[0];
    const float* cov0   = (const float*)d_in[1];
    const float* meas   = (const float*)d_in[2];
    const float* Fm     = (const float*)d_in[3];
    const float* Hm     = (const float*)d_in[4];
    const float* Qm     = (const float*)d_in[5];
    const float* Rm     = (const float*)d_in[6];
    float* out = (float*)d_out;

    const int B = in_sizes[0] / S_DIM;               // 2048
    const int T = in_sizes[2] / (B * O_DIM);         // 64

    const int grid = (B + CW - 1) / CW;              // 256 blocks
    kf_fused<<<dim3(grid), dim3(NTHR), 0, stream>>>(
        state0, cov0, meas, Fm, Hm, Qm, Rm, out, T, B);
}